// Round 9
// baseline (178.459 us; speedup 1.0000x reference)
//
#include <hip/hip_runtime.h>

typedef __bf16 bf16x8 __attribute__((ext_vector_type(8)));
typedef float f32x4 __attribute__((ext_vector_type(4)));
typedef float f32x16 __attribute__((ext_vector_type(16)));
typedef unsigned int uint32;
typedef unsigned short u16;

#define NST 21
#define TOK 1003
#define SCL 0.3606737602222409f  // 0.25*log2(e); softmax = exp2(s), shift-free

union U4B { uint4 u; bf16x8 b; };

__device__ __forceinline__ uint32 pkbf(float a, float b) {  // RTNE pack
  uint32 ua = __float_as_uint(a), ub = __float_as_uint(b);
  ua += 0x7fffu + ((ua >> 16) & 1u);
  ub += 0x7fffu + ((ub >> 16) & 1u);
  return (ua >> 16) | (ub & 0xffff0000u);
}
__device__ __forceinline__ u16 bf1(float a) {
  uint32 u = __float_as_uint(a);
  u += 0x7fffu + ((u >> 16) & 1u);
  return (u16)(u >> 16);
}
// 1-instr truncating pack: lo16 = lo.hi16, hi16 = hi.hi16 (CK idiom)
__device__ __forceinline__ uint32 pkperm(float lo, float hi) {
  return __builtin_amdgcn_perm(__float_as_uint(hi), __float_as_uint(lo), 0x07060302u);
}
// half-wave swap: a' = {a.lanes0-31 | b.lanes0-31}, b' = {a.lanes32-63 | b.lanes32-63}
__device__ __forceinline__ void plswap(uint32& a, uint32& b) {
#if __has_builtin(__builtin_amdgcn_permlane32_swap)
  typedef unsigned int uu2 __attribute__((ext_vector_type(2)));
  uu2 r = __builtin_amdgcn_permlane32_swap(a, b, false, false);
  a = r.x; b = r.y;
#else
  asm volatile("v_permlane32_swap_b32 %0, %1" : "+v"(a), "+v"(b));
#endif
}

// =====================================================================
// prep: (a) 5 weight transposes -> bf16 WtAll (40 blocks, 8 per matrix),
// (b) station projections Q_st->Qm rows<21, K_s/V_s (+zero pad rows
// 21..32). grid 552 = 40 + 512
// =====================================================================
__global__ __launch_bounds__(256) void prep(
    const float* __restrict__ q, const float* __restrict__ hx,
    const float* __restrict__ W0, const float* __restrict__ W1,
    const float* __restrict__ W2, const float* __restrict__ W3,
    const float* __restrict__ W4, const float* __restrict__ Wqst,
    const float* __restrict__ Wks, const float* __restrict__ Wvs,
    u16* __restrict__ WtAll, u16* __restrict__ Qm,
    u16* __restrict__ Ks, u16* __restrict__ Vs) {
  int bid = blockIdx.x, tid = threadIdx.x;
  __shared__ float xq2[2][128], xh2[2][128];
  if (bid < 40) {
    int w = bid >> 3, seg = bid & 7;
    const float* W = (w == 0) ? W0 : (w == 1) ? W1 : (w == 2) ? W2
                     : (w == 3) ? W3 : W4;
    u16* dst = WtAll + w * 16384;
#pragma unroll
    for (int it = 0; it < 8; ++it) {
      int i = seg * 2048 + it * 256 + tid;  // 0..16383
      int inner = i & 127, outer = i >> 7;
      float v;
      if (w < 4) {
        int h = outer >> 4, k = outer & 15;
        v = W[h * 2048 + inner * 16 + k];
      } else {
        v = W[inner * 128 + outer];
      }
      dst[outer * 128 + inner] = bf1(v);
    }
  } else {
    int t2 = bid - 40;              // 0..511
    int sub = tid >> 7, col = tid & 127;
    int hh = col >> 4, k = col & 15;
    int bs2 = t2 * 2 + sub;         // 0..1023
    int b2 = bs2 >> 5, s = bs2 & 31;
    if (s < NST) {
      xq2[sub][col] = q[(size_t)(b2 * 1024 + s) * 128 + col];
      xh2[sub][col] = hx[(size_t)(b2 * 1024 + s) * 128 + col];
    }
    __syncthreads();
    if (s < NST) {
      const float* Wq = Wqst + hh * 2048 + k;
      const float* Wk = Wks + hh * 2048 + k;
      const float* Wv = Wvs + hh * 2048 + k;
      float dq = 0.f, dk_ = 0.f, dv = 0.f;
#pragma unroll 8
      for (int d = 0; d < 128; ++d) {
        float xq = xq2[sub][d], xh = xh2[sub][d];
        dq = fmaf(xq, Wq[d * 16], dq);
        dk_ = fmaf(xh, Wk[d * 16], dk_);
        dv = fmaf(xh, Wv[d * 16], dv);
      }
      Qm[(((size_t)hh * 32 + b2) * 1024 + s) * 16 + k] = bf1(dq * SCL);
      Ks[(((size_t)hh * 32 + b2) * 32 + s) * 16 + k] = bf1(dk_);
      Vs[(((size_t)hh * 32 + b2) * 16 + k) * 32 + s] = bf1(dv);
    } else {
      Ks[(((size_t)hh * 32 + b2) * 32 + s) * 16 + k] = 0;
      Vs[(((size_t)hh * 32 + b2) * 16 + k) * 32 + s] = 0;
    }
  }
}

// =====================================================================
// proj_pair: one block computes BOTH projections sharing an A tile.
// pg=0: q -> Qm (mode0: scaled, skip tok<21) and Qts (mode1: scaled)
// pg=1: hx -> Kc (mode2) and Vc (mode3: transposed [h][b][k16][n1024])
// Modes 0-2 use SWAPPED MFMA operands (A/B fragment layouts identical
// for 16x16x32) so each thread's 4 acc values are k-contiguous ->
// uint2 stores; a wave writes one contiguous 512B block per nt.
// grid 1024 = 2 x 512
// =====================================================================
__global__ __launch_bounds__(256) void proj_pair(
    const float* __restrict__ q, const float* __restrict__ hx,
    const u16* __restrict__ WtAll, u16* __restrict__ Qm,
    u16* __restrict__ Qts, u16* __restrict__ Kc, u16* __restrict__ Vc) {
  __shared__ u16 Wl[128 * 136];
  int pg = blockIdx.x >> 9, mb = blockIdx.x & 511;
  int m0 = mb * 64;
  const float* A = pg ? hx : q;
  int tid = threadIdx.x;
  int wave = tid >> 6, lane = tid & 63;
  int quad = lane >> 4, l15 = lane & 15;
  int mrow = m0 + wave * 16 + l15;

  U4B af[4];
#pragma unroll
  for (int dk = 0; dk < 4; ++dk) {
    const float* Af = A + (size_t)mrow * 128 + dk * 32 + quad * 8;
    float4 a = *(const float4*)Af;
    float4 b = *(const float4*)(Af + 4);
    af[dk].u = make_uint4(pkbf(a.x, a.y), pkbf(a.z, a.w),
                          pkbf(b.x, b.y), pkbf(b.z, b.w));
  }

  int gbase = m0 + wave * 16 + quad * 4;   // mode-3 path (unswapped)
  int bb = gbase >> 10, n0 = gbase & 1023;
  int token = mrow;                         // modes 0-2 path (swapped)
  int bb2 = token >> 10, tn = token & 1023;

#pragma unroll
  for (int s = 0; s < 2; ++s) {
    int mode = pg * 2 + s;
    const u16* WtG = WtAll + mode * 16384;
    if (s) __syncthreads();  // all Wl reads of s=0 done before restage
#pragma unroll
    for (int r = 0; r < 8; ++r) {
      int i = r * 256 + tid;
      int e = i >> 4, j = i & 15;
      *(uint4*)&Wl[e * 136 + j * 8] = *(const uint4*)(WtG + e * 128 + j * 8);
    }
    __syncthreads();

    f32x4 c[8];
#pragma unroll
    for (int nt = 0; nt < 8; ++nt)
#pragma unroll
      for (int r = 0; r < 4; ++r) c[nt][r] = 0.f;
#pragma unroll
    for (int dk = 0; dk < 4; ++dk)
#pragma unroll
      for (int nt = 0; nt < 8; ++nt) {
        U4B bg;
        bg.u = *(const uint4*)&Wl[(nt * 16 + l15) * 136 + dk * 32 + quad * 8];
        if (mode == 3)
          c[nt] = __builtin_amdgcn_mfma_f32_16x16x32_bf16(af[dk].b, bg.b, c[nt], 0, 0, 0);
        else
          c[nt] = __builtin_amdgcn_mfma_f32_16x16x32_bf16(bg.b, af[dk].b, c[nt], 0, 0, 0);
      }

    if (mode == 3) {
#pragma unroll
      for (int nt = 0; nt < 8; ++nt) {
        uint2 w2 = make_uint2(pkbf(c[nt][0], c[nt][1]), pkbf(c[nt][2], c[nt][3]));
        *(uint2*)(Vc + (((size_t)nt * 32 + bb) * 16 + l15) * 1024 + n0) = w2;
      }
    } else {
      float scale = (mode <= 1) ? SCL : 1.0f;
      u16* dstp = (mode == 0) ? Qm : (mode == 1) ? Qts : Kc;
      if (mode != 0 || tn >= NST) {  // prep owns station rows of Qm
#pragma unroll
        for (int nt = 0; nt < 8; ++nt) {
          uint2 w2 = make_uint2(pkbf(c[nt][0] * scale, c[nt][1] * scale),
                                pkbf(c[nt][2] * scale, c[nt][3] * scale));
          *(uint2*)(dstp + (((size_t)nt * 32 + bb2) * 1024 + tn) * 16 + quad * 4) = w2;
        }
      }
    }
  }
}

// =====================================================================
// outproj: out(64 x 128) f32 = heads_bf16(64x128) @ W_out^T
// heads is [h][b*1024+n][16] (head-major): column c = h*16+k ->
// h = dk*2+(quad>>1), k0 = (quad&1)*8.
// Swapped MFMA operands -> e-contiguous acc -> float4 stores.
// =====================================================================
__global__ __launch_bounds__(256) void outproj(
    const u16* __restrict__ heads, const u16* __restrict__ WtAll,
    float* __restrict__ out) {
  __shared__ u16 Wl[128 * 136];
  const u16* WtG = WtAll + 4 * 16384;
  int tid = threadIdx.x;
#pragma unroll
  for (int r = 0; r < 8; ++r) {
    int i = r * 256 + tid;
    int e = i >> 4, j = i & 15;
    *(uint4*)&Wl[e * 136 + j * 8] = *(const uint4*)(WtG + e * 128 + j * 8);
  }
  __syncthreads();
  int wave = tid >> 6, lane = tid & 63;
  int quad = lane >> 4, l15 = lane & 15;
  int m0 = blockIdx.x * 64;
  int mrow = m0 + wave * 16 + l15;

  f32x4 c[8];
#pragma unroll
  for (int nt = 0; nt < 8; ++nt)
#pragma unroll
    for (int r = 0; r < 4; ++r) c[nt][r] = 0.f;
#pragma unroll
  for (int dk = 0; dk < 4; ++dk) {
    U4B af;
    int h2 = dk * 2 + (quad >> 1);
    int k0 = (quad & 1) * 8;
    af.u = *(const uint4*)(heads + ((size_t)h2 * 32768 + mrow) * 16 + k0);
#pragma unroll
    for (int nt = 0; nt < 8; ++nt) {
      U4B bg;
      bg.u = *(const uint4*)&Wl[(nt * 16 + l15) * 136 + dk * 32 + quad * 8];
      c[nt] = __builtin_amdgcn_mfma_f32_16x16x32_bf16(bg.b, af.b, c[nt], 0, 0, 0);
    }
  }
  // thread holds out[token=mrow][e = nt*16 + quad*4 + r]
#pragma unroll
  for (int nt = 0; nt < 8; ++nt)
    *(f32x4*)(out + (size_t)mrow * 128 + nt * 16 + quad * 4) = c[nt];
}

// =====================================================================
// attn_main v6 (occupancy via block shape): 512 threads (8 waves),
// QBLK=256, grid 1024 = 4 qc x 256 hb. Per-CU: min(LDS 160/20=8,
// waveslots 32/8=4) = 4 blocks = 32 waves/CU (2x the r8 residency).
// Per-wave compute/math/epilogue byte-identical to the verified r8
// kernel (2 barriers/kb, T14 reg prefetch now uint2/thread, 2-deep kt
// pipeline, ones rows in LDS). Also halves redundant K/V refetch
// (4 qc blocks per hb instead of 8).
// =====================================================================
__global__ __launch_bounds__(512, 8) void attn_main(
    const u16* __restrict__ Qm, const u16* __restrict__ Qts,
    const u16* __restrict__ Kc, const u16* __restrict__ Vc,
    const u16* __restrict__ Ks, const u16* __restrict__ Vs,
    u16* __restrict__ heads) {
  int bx = blockIdx.x;
  int hb = bx & 255, qc = bx >> 8;   // qc 0..3
  int h = hb >> 5, b = hb & 31;
  int tid = threadIdx.x;
  int wave = tid >> 6, lane = tid & 63;
  int l5 = lane >> 5, l31 = lane & 31;

  __shared__ u16 Kl[128 * 26];   // [key][26]: 52B rows, 13-bank step
  __shared__ u16 Vl[32 * 140];   // rows 0-15: V^T tile; rows 16-31: 1.0
  __shared__ u16 KsL[32 * 26];   // station keys
  __shared__ u16 VsL[32 * 44];   // rows 0-15: V_s^T; rows 16-31: 1.0

  const u16* Qbase = Qm + ((size_t)(h * 32 + b)) * 16384;
  const u16* QtsB = Qts + ((size_t)(h * 32 + b)) * 16384;
  const u16* Kbase = Kc + ((size_t)(h * 32 + b)) * 16384;
  const u16* Vbase = Vc + ((size_t)(h * 32 + b)) * 16384;
  const u16* KsB = Ks + (size_t)(h * 32 + b) * 512;
  const u16* VsB = Vs + (size_t)(h * 32 + b) * 512;

  uint4 ones4 = make_uint4(0x3F803F80u, 0x3F803F80u, 0x3F803F80u, 0x3F803F80u);

  // ---- stage station K/V + ones rows (visible after first barrier) ----
  if (tid < 64) {
    int key = tid >> 1, half = tid & 1;
    *(uint4*)&KsL[key * 26 + half * 8] = *(const uint4*)(KsB + key * 16 + half * 8);
  } else if (tid < 128) {
    int t = tid - 64;
    int d = t >> 2, kg = t & 3;
    *(uint4*)&VsL[d * 44 + kg * 8] = *(const uint4*)(VsB + d * 32 + kg * 8);
  } else if (tid < 192) {
    int t = tid - 128;  // VsL ones rows 16-31, cols 0-31: 64 x b128
    *(uint4*)&VsL[(16 + (t >> 2)) * 44 + (t & 3) * 8] = ones4;
  }
  // Vl ones rows 16-31, cols 0-127 (256 threads x b128); persist across
  // all kb stages (staging only writes rows 0-15).
  if (tid < 256)
    *(uint4*)&Vl[(16 + (tid >> 4)) * 140 + (tid & 15) * 8] = ones4;

  // T14 prefetch: main-loop tile 0, 8B per thread (512 threads)
  int skey = tid >> 2, shalf = tid & 3;   // K: 128 rows x 32B
  int sd = tid >> 5, skg = tid & 31;      // V: 16 rows x 256B (tile cols)
  uint2 kpre = *(const uint2*)(Kbase + (size_t)skey * 16 + shalf * 4);
  uint2 vpre = *(const uint2*)(Vbase + (size_t)sd * 1024 + skg * 4);

  int qw0 = qc * 256 + wave * 32;
  int qrow = qw0 + l31;

  f32x16 zero16;
#pragma unroll
  for (int i = 0; i < 16; ++i) zero16[i] = 0.f;

  // ---- station pass first: contrib[8] = (P_s V_s / la_s) rows ----
  U4B qf;
  qf.u = *(const uint4*)(QtsB + (size_t)qrow * 16 + l5 * 8);
  __syncthreads();  // KsL/VsL (+ones) visible
  float contrib[8];
  {
    U4B af;
    af.u = *(const uint4*)&KsL[l31 * 26 + l5 * 8];
    f32x16 c0 =
        __builtin_amdgcn_mfma_f32_32x32x16_bf16(af.b, qf.b, zero16, 0, 0, 0);
    uint32 w[8];
#pragma unroll
    for (int g = 0; g < 4; ++g) {
      float p0 = __builtin_amdgcn_exp2f(c0[4 * g + 0]);
      float p1 = __builtin_amdgcn_exp2f(c0[4 * g + 1]);
      float p2 = __builtin_amdgcn_exp2f(c0[4 * g + 2]);
      float p3 = __builtin_amdgcn_exp2f(c0[4 * g + 3]);
      int kb0 = 8 * g + 4 * l5;  // zero keys >= 21 (pad rows)
      p0 = (kb0 + 0 >= NST) ? 0.f : p0;
      p1 = (kb0 + 1 >= NST) ? 0.f : p1;
      p2 = (kb0 + 2 >= NST) ? 0.f : p2;
      p3 = (kb0 + 3 >= NST) ? 0.f : p3;
      w[2 * g] = pkperm(p0, p1);
      w[2 * g + 1] = pkperm(p2, p3);
    }
    plswap(w[0], w[2]); plswap(w[1], w[3]);
    plswap(w[4], w[6]); plswap(w[5], w[7]);
    U4B b1, b2, a1, a2;
    b1.u = make_uint4(w[0], w[1], w[2], w[3]);
    b2.u = make_uint4(w[4], w[5], w[6], w[7]);
    a1.u = *(const uint4*)&VsL[l31 * 44 + l5 * 8];
    a2.u = *(const uint4*)&VsL[l31 * 44 + 16 + l5 * 8];
    f32x16 acc2 =
        __builtin_amdgcn_mfma_f32_32x32x16_bf16(a1.b, b1.b, zero16, 0, 0, 0);
    acc2 = __builtin_amdgcn_mfma_f32_32x32x16_bf16(a2.b, b2.b, acc2, 0, 0, 0);
    float rla2 = __builtin_amdgcn_rcpf(acc2[8]);  // ones row m=16+4*l5
#pragma unroll
    for (int r = 0; r < 8; ++r) contrib[r] = acc2[r] * rla2;
  }

  // ---- main pass over Kc/Vc ----
  qf.u = *(const uint4*)(Qbase + (size_t)qrow * 16 + l5 * 8);
  f32x16 acc;
#pragma unroll
  for (int i = 0; i < 16; ++i) acc[i] = 0.f;

#pragma unroll 1
  for (int kb = 0; kb < 8; ++kb) {
    __syncthreads();  // previous tile's compute done reading Kl/Vl
    *(uint2*)&Kl[skey * 26 + shalf * 4] = kpre;
    *(uint2*)&Vl[sd * 140 + skg * 4] = vpre;
    if (kb < 7) {  // issue next tile; completes under this tile's compute
      int j0n = (kb + 1) * 128;
      kpre = *(const uint2*)(Kbase + (size_t)(j0n + skey) * 16 + shalf * 4);
      vpre = *(const uint2*)(Vbase + (size_t)sd * 1024 + j0n + skg * 4);
    }
    __syncthreads();

    // 2-deep pipeline: S(kt+1) issues before VALU block of kt
    U4B af0;
    af0.u = *(const uint4*)&Kl[l31 * 26 + l5 * 8];
    f32x16 c0 =
        __builtin_amdgcn_mfma_f32_32x32x16_bf16(af0.b, qf.b, zero16, 0, 0, 0);
#pragma unroll
    for (int kt = 0; kt < 4; ++kt) {
      f32x16 cn;
      if (kt < 3) {
        U4B afn;
        afn.u = *(const uint4*)&Kl[((kt + 1) * 32 + l31) * 26 + l5 * 8];
        cn = __builtin_amdgcn_mfma_f32_32x32x16_bf16(afn.b, qf.b, zero16, 0, 0, 0);
      }
      int key0 = kt * 32;
      bool masked = (kb == 0) && (kt == 0);
      uint32 w[8];
#pragma unroll
      for (int g = 0; g < 4; ++g) {
        float p0 = __builtin_amdgcn_exp2f(c0[4 * g + 0]);
        float p1 = __builtin_amdgcn_exp2f(c0[4 * g + 1]);
        float p2 = __builtin_amdgcn_exp2f(c0[4 * g + 2]);
        float p3 = __builtin_amdgcn_exp2f(c0[4 * g + 3]);
        if (masked) {  // key index of value r is r + 8*g + 4*l5; zero keys<21
          int kb0 = 8 * g + 4 * l5;
          p0 = (kb0 + 0 < NST) ? 0.f : p0;
          p1 = (kb0 + 1 < NST) ? 0.f : p1;
          p2 = (kb0 + 2 < NST) ? 0.f : p2;
          p3 = (kb0 + 3 < NST) ? 0.f : p3;
        }
        w[2 * g] = pkperm(p0, p1);
        w[2 * g + 1] = pkperm(p2, p3);
      }
      plswap(w[0], w[2]); plswap(w[1], w[3]);
      plswap(w[4], w[6]); plswap(w[5], w[7]);
      U4B b1, b2, a1, a2;
      b1.u = make_uint4(w[0], w[1], w[2], w[3]);
      b2.u = make_uint4(w[4], w[5], w[6], w[7]);
      a1.u = *(const uint4*)&Vl[l31 * 140 + key0 + l5 * 8];
      a2.u = *(const uint4*)&Vl[l31 * 140 + key0 + 16 + l5 * 8];
      acc = __builtin_amdgcn_mfma_f32_32x32x16_bf16(a1.b, b1.b, acc, 0, 0, 0);
      acc = __builtin_amdgcn_mfma_f32_32x32x16_bf16(a2.b, b2.b, acc, 0, 0, 0);
      if (kt < 3) c0 = cn;
    }
  }

  // ---- epilogue: heads bf16, layout [h][b][n][16] (block-contiguous) ----
  // acc regs 0-3: d = 4*l5 + r; regs 4-7: d = 8 + 4*l5 + (r-4);
  // regs 8-15: la rows (all equal) -> use acc[8].
  {
    float rla = __builtin_amdgcn_rcpf(acc[8]);
    bool tok = (qrow >= NST);
    float v0 = acc[0] * rla + (tok ? contrib[0] : 0.f);
    float v1 = acc[1] * rla + (tok ? contrib[1] : 0.f);
    float v2 = acc[2] * rla + (tok ? contrib[2] : 0.f);
    float v3 = acc[3] * rla + (tok ? contrib[3] : 0.f);
    float v4 = acc[4] * rla + (tok ? contrib[4] : 0.f);
    float v5 = acc[5] * rla + (tok ? contrib[5] : 0.f);
    float v6 = acc[6] * rla + (tok ? contrib[6] : 0.f);
    float v7 = acc[7] * rla + (tok ? contrib[7] : 0.f);
    u16* hrow = heads + (((size_t)(h * 32 + b)) * 1024 + qrow) * 16;
    *(uint2*)(hrow + 4 * l5) = make_uint2(pkbf(v0, v1), pkbf(v2, v3));
    *(uint2*)(hrow + 8 + 4 * l5) = make_uint2(pkbf(v4, v5), pkbf(v6, v7));
  }
}

// =====================================================================
extern "C" void kernel_launch(void* const* d_in, const int* in_sizes, int n_in,
                              void* d_out, int out_size, void* d_ws,
                              size_t ws_size, hipStream_t stream) {
  (void)in_sizes; (void)n_in; (void)out_size; (void)ws_size;
  const float* q     = (const float*)d_in[0];
  const float* hx    = (const float*)d_in[1];
  const float* W_qts = (const float*)d_in[2];  // W_query_custom   -> Q_ts
  const float* W_qtt = (const float*)d_in[3];  // W_query_custom_1 -> Q_tt
  const float* W_kc  = (const float*)d_in[4];
  const float* W_vc  = (const float*)d_in[5];
  const float* W_qst = (const float*)d_in[6];  // W_query_charge_1 -> Q_st
  const float* W_ks  = (const float*)d_in[7];
  const float* W_vs  = (const float*)d_in[8];
  const float* W_out = (const float*)d_in[9];

  char* ws = (char*)d_ws;
  u16* heads = (u16*)(ws + 0);          // bf16 heads [h][b][n][16]
  u16* Qm    = (u16*)(ws + 16777216);   // [h][b][1024][16]
  u16* Qts   = (u16*)(ws + 25165824);
  u16* Kc    = (u16*)(ws + 33554432);   // [h][b][1024][16]
  u16* Vc    = (u16*)(ws + 41943040);   // [h][b][16][1024] (transposed)
  u16* Ks    = (u16*)(ws + 50331648);   // [h][b][32][16]
  u16* Vs    = (u16*)(ws + 50593792);   // [h][b][16][32]
  u16* WtAll = (u16*)(ws + 50855936);   // 5 x 128x128 bf16

  hipLaunchKernelGGL(prep, dim3(552), dim3(256), 0, stream,
                     q, hx, W_qtt, W_qts, W_kc, W_vc, W_out, W_qst, W_ks, W_vs,
                     WtAll, Qm, Ks, Vs);
  hipLaunchKernelGGL(proj_pair, dim3(1024), dim3(256), 0, stream,
                     q, hx, WtAll, Qm, Qts, Kc, Vc);
  hipLaunchKernelGGL(attn_main, dim3(1024), dim3(512), 0, stream,
                     Qm, Qts, Kc, Vc, Ks, Vs, heads);
  hipLaunchKernelGGL(outproj, dim3(512), dim3(256), 0, stream,
                     heads, WtAll, (float*)d_out);
}

// Round 10
// 154.891 us; speedup vs baseline: 1.1522x; 1.1522x over previous
//
#include <hip/hip_runtime.h>

typedef __bf16 bf16x8 __attribute__((ext_vector_type(8)));
typedef float f32x4 __attribute__((ext_vector_type(4)));
typedef float f32x16 __attribute__((ext_vector_type(16)));
typedef unsigned int uint32;
typedef unsigned short u16;

#define NST 21
#define TOK 1003
#define SCL 0.3606737602222409f  // 0.25*log2(e); softmax = exp2(s), shift-free

union U4B { uint4 u; bf16x8 b; };

__device__ __forceinline__ uint32 pkbf(float a, float b) {  // RTNE pack
  uint32 ua = __float_as_uint(a), ub = __float_as_uint(b);
  ua += 0x7fffu + ((ua >> 16) & 1u);
  ub += 0x7fffu + ((ub >> 16) & 1u);
  return (ua >> 16) | (ub & 0xffff0000u);
}
__device__ __forceinline__ u16 bf1(float a) {
  uint32 u = __float_as_uint(a);
  u += 0x7fffu + ((u >> 16) & 1u);
  return (u16)(u >> 16);
}
// 1-instr truncating pack: lo16 = lo.hi16, hi16 = hi.hi16 (CK idiom)
__device__ __forceinline__ uint32 pkperm(float lo, float hi) {
  return __builtin_amdgcn_perm(__float_as_uint(hi), __float_as_uint(lo), 0x07060302u);
}
// half-wave swap: a' = {a.lanes0-31 | b.lanes0-31}, b' = {a.lanes32-63 | b.lanes32-63}
__device__ __forceinline__ void plswap(uint32& a, uint32& b) {
#if __has_builtin(__builtin_amdgcn_permlane32_swap)
  typedef unsigned int uu2 __attribute__((ext_vector_type(2)));
  uu2 r = __builtin_amdgcn_permlane32_swap(a, b, false, false);
  a = r.x; b = r.y;
#else
  asm volatile("v_permlane32_swap_b32 %0, %1" : "+v"(a), "+v"(b));
#endif
}

// =====================================================================
// prep: (a) 5 weight transposes -> bf16 WtAll (40 blocks, 8 per matrix),
// (b) station projections Q_st->Qm rows<21, K_s/V_s (+zero pad rows
// 21..32). grid 552 = 40 + 512
// =====================================================================
__global__ __launch_bounds__(256) void prep(
    const float* __restrict__ q, const float* __restrict__ hx,
    const float* __restrict__ W0, const float* __restrict__ W1,
    const float* __restrict__ W2, const float* __restrict__ W3,
    const float* __restrict__ W4, const float* __restrict__ Wqst,
    const float* __restrict__ Wks, const float* __restrict__ Wvs,
    u16* __restrict__ WtAll, u16* __restrict__ Qm,
    u16* __restrict__ Ks, u16* __restrict__ Vs) {
  int bid = blockIdx.x, tid = threadIdx.x;
  __shared__ float xq2[2][128], xh2[2][128];
  if (bid < 40) {
    int w = bid >> 3, seg = bid & 7;
    const float* W = (w == 0) ? W0 : (w == 1) ? W1 : (w == 2) ? W2
                     : (w == 3) ? W3 : W4;
    u16* dst = WtAll + w * 16384;
#pragma unroll
    for (int it = 0; it < 8; ++it) {
      int i = seg * 2048 + it * 256 + tid;  // 0..16383
      int inner = i & 127, outer = i >> 7;
      float v;
      if (w < 4) {
        int h = outer >> 4, k = outer & 15;
        v = W[h * 2048 + inner * 16 + k];
      } else {
        v = W[inner * 128 + outer];
      }
      dst[outer * 128 + inner] = bf1(v);
    }
  } else {
    int t2 = bid - 40;              // 0..511
    int sub = tid >> 7, col = tid & 127;
    int hh = col >> 4, k = col & 15;
    int bs2 = t2 * 2 + sub;         // 0..1023
    int b2 = bs2 >> 5, s = bs2 & 31;
    if (s < NST) {
      xq2[sub][col] = q[(size_t)(b2 * 1024 + s) * 128 + col];
      xh2[sub][col] = hx[(size_t)(b2 * 1024 + s) * 128 + col];
    }
    __syncthreads();
    if (s < NST) {
      const float* Wq = Wqst + hh * 2048 + k;
      const float* Wk = Wks + hh * 2048 + k;
      const float* Wv = Wvs + hh * 2048 + k;
      float dq = 0.f, dk_ = 0.f, dv = 0.f;
#pragma unroll 8
      for (int d = 0; d < 128; ++d) {
        float xq = xq2[sub][d], xh = xh2[sub][d];
        dq = fmaf(xq, Wq[d * 16], dq);
        dk_ = fmaf(xh, Wk[d * 16], dk_);
        dv = fmaf(xh, Wv[d * 16], dv);
      }
      Qm[(((size_t)hh * 32 + b2) * 1024 + s) * 16 + k] = bf1(dq * SCL);
      Ks[(((size_t)hh * 32 + b2) * 32 + s) * 16 + k] = bf1(dk_);
      Vs[(((size_t)hh * 32 + b2) * 16 + k) * 32 + s] = bf1(dv);
    } else {
      Ks[(((size_t)hh * 32 + b2) * 32 + s) * 16 + k] = 0;
      Vs[(((size_t)hh * 32 + b2) * 16 + k) * 32 + s] = 0;
    }
  }
}

// =====================================================================
// proj_pair: one block computes BOTH projections sharing an A tile.
// pg=0: q -> Qm (mode0: scaled, skip tok<21) and Qts (mode1: scaled)
// pg=1: hx -> Kc (mode2) and Vc (mode3: transposed [h][b][k16][n1024])
// Modes 0-2 use SWAPPED MFMA operands (A/B fragment layouts identical
// for 16x16x32) so each thread's 4 acc values are k-contiguous ->
// uint2 stores; a wave writes one contiguous 512B block per nt.
// grid 1024 = 2 x 512
// =====================================================================
__global__ __launch_bounds__(256) void proj_pair(
    const float* __restrict__ q, const float* __restrict__ hx,
    const u16* __restrict__ WtAll, u16* __restrict__ Qm,
    u16* __restrict__ Qts, u16* __restrict__ Kc, u16* __restrict__ Vc) {
  __shared__ u16 Wl[128 * 136];
  int pg = blockIdx.x >> 9, mb = blockIdx.x & 511;
  int m0 = mb * 64;
  const float* A = pg ? hx : q;
  int tid = threadIdx.x;
  int wave = tid >> 6, lane = tid & 63;
  int quad = lane >> 4, l15 = lane & 15;
  int mrow = m0 + wave * 16 + l15;

  U4B af[4];
#pragma unroll
  for (int dk = 0; dk < 4; ++dk) {
    const float* Af = A + (size_t)mrow * 128 + dk * 32 + quad * 8;
    float4 a = *(const float4*)Af;
    float4 b = *(const float4*)(Af + 4);
    af[dk].u = make_uint4(pkbf(a.x, a.y), pkbf(a.z, a.w),
                          pkbf(b.x, b.y), pkbf(b.z, b.w));
  }

  int gbase = m0 + wave * 16 + quad * 4;   // mode-3 path (unswapped)
  int bb = gbase >> 10, n0 = gbase & 1023;
  int token = mrow;                         // modes 0-2 path (swapped)
  int bb2 = token >> 10, tn = token & 1023;

#pragma unroll
  for (int s = 0; s < 2; ++s) {
    int mode = pg * 2 + s;
    const u16* WtG = WtAll + mode * 16384;
    if (s) __syncthreads();  // all Wl reads of s=0 done before restage
#pragma unroll
    for (int r = 0; r < 8; ++r) {
      int i = r * 256 + tid;
      int e = i >> 4, j = i & 15;
      *(uint4*)&Wl[e * 136 + j * 8] = *(const uint4*)(WtG + e * 128 + j * 8);
    }
    __syncthreads();

    f32x4 c[8];
#pragma unroll
    for (int nt = 0; nt < 8; ++nt)
#pragma unroll
      for (int r = 0; r < 4; ++r) c[nt][r] = 0.f;
#pragma unroll
    for (int dk = 0; dk < 4; ++dk)
#pragma unroll
      for (int nt = 0; nt < 8; ++nt) {
        U4B bg;
        bg.u = *(const uint4*)&Wl[(nt * 16 + l15) * 136 + dk * 32 + quad * 8];
        if (mode == 3)
          c[nt] = __builtin_amdgcn_mfma_f32_16x16x32_bf16(af[dk].b, bg.b, c[nt], 0, 0, 0);
        else
          c[nt] = __builtin_amdgcn_mfma_f32_16x16x32_bf16(bg.b, af[dk].b, c[nt], 0, 0, 0);
      }

    if (mode == 3) {
#pragma unroll
      for (int nt = 0; nt < 8; ++nt) {
        uint2 w2 = make_uint2(pkbf(c[nt][0], c[nt][1]), pkbf(c[nt][2], c[nt][3]));
        *(uint2*)(Vc + (((size_t)nt * 32 + bb) * 16 + l15) * 1024 + n0) = w2;
      }
    } else {
      float scale = (mode <= 1) ? SCL : 1.0f;
      u16* dstp = (mode == 0) ? Qm : (mode == 1) ? Qts : Kc;
      if (mode != 0 || tn >= NST) {  // prep owns station rows of Qm
#pragma unroll
        for (int nt = 0; nt < 8; ++nt) {
          uint2 w2 = make_uint2(pkbf(c[nt][0] * scale, c[nt][1] * scale),
                                pkbf(c[nt][2] * scale, c[nt][3] * scale));
          *(uint2*)(dstp + (((size_t)nt * 32 + bb2) * 1024 + tn) * 16 + quad * 4) = w2;
        }
      }
    }
  }
}

// =====================================================================
// outproj: out(64 x 128) f32 = heads_bf16(64x128) @ W_out^T
// heads is [h][b*1024+n][16] (head-major): column c = h*16+k ->
// h = dk*2+(quad>>1), k0 = (quad&1)*8.
// Swapped MFMA operands -> e-contiguous acc -> float4 stores.
// =====================================================================
__global__ __launch_bounds__(256) void outproj(
    const u16* __restrict__ heads, const u16* __restrict__ WtAll,
    float* __restrict__ out) {
  __shared__ u16 Wl[128 * 136];
  const u16* WtG = WtAll + 4 * 16384;
  int tid = threadIdx.x;
#pragma unroll
  for (int r = 0; r < 8; ++r) {
    int i = r * 256 + tid;
    int e = i >> 4, j = i & 15;
    *(uint4*)&Wl[e * 136 + j * 8] = *(const uint4*)(WtG + e * 128 + j * 8);
  }
  __syncthreads();
  int wave = tid >> 6, lane = tid & 63;
  int quad = lane >> 4, l15 = lane & 15;
  int m0 = blockIdx.x * 64;
  int mrow = m0 + wave * 16 + l15;

  f32x4 c[8];
#pragma unroll
  for (int nt = 0; nt < 8; ++nt)
#pragma unroll
    for (int r = 0; r < 4; ++r) c[nt][r] = 0.f;
#pragma unroll
  for (int dk = 0; dk < 4; ++dk) {
    U4B af;
    int h2 = dk * 2 + (quad >> 1);
    int k0 = (quad & 1) * 8;
    af.u = *(const uint4*)(heads + ((size_t)h2 * 32768 + mrow) * 16 + k0);
#pragma unroll
    for (int nt = 0; nt < 8; ++nt) {
      U4B bg;
      bg.u = *(const uint4*)&Wl[(nt * 16 + l15) * 136 + dk * 32 + quad * 8];
      c[nt] = __builtin_amdgcn_mfma_f32_16x16x32_bf16(bg.b, af.b, c[nt], 0, 0, 0);
    }
  }
  // thread holds out[token=mrow][e = nt*16 + quad*4 + r]
#pragma unroll
  for (int nt = 0; nt < 8; ++nt)
    *(f32x4*)(out + (size_t)mrow * 128 + nt * 16 + quad * 4) = c[nt];
}

// =====================================================================
// attn_main v6b: identical to v6 (512 threads, QBLK=256, grid 1024)
// EXCEPT __launch_bounds__(512, 4): v6's (512,8) starved the allocator
// to 32 VGPR -> accumulator spill to scratch (WRITE_SIZE 51->110MB,
// dur 45.6->65.7). Cap 128 VGPR lets the natural ~48-64 VGPR allocation
// stand; HW can still co-schedule 8 waves/SIMD if VGPR<=64.
// =====================================================================
__global__ __launch_bounds__(512, 4) void attn_main(
    const u16* __restrict__ Qm, const u16* __restrict__ Qts,
    const u16* __restrict__ Kc, const u16* __restrict__ Vc,
    const u16* __restrict__ Ks, const u16* __restrict__ Vs,
    u16* __restrict__ heads) {
  int bx = blockIdx.x;
  int hb = bx & 255, qc = bx >> 8;   // qc 0..3
  int h = hb >> 5, b = hb & 31;
  int tid = threadIdx.x;
  int wave = tid >> 6, lane = tid & 63;
  int l5 = lane >> 5, l31 = lane & 31;

  __shared__ u16 Kl[128 * 26];   // [key][26]: 52B rows, 13-bank step
  __shared__ u16 Vl[32 * 140];   // rows 0-15: V^T tile; rows 16-31: 1.0
  __shared__ u16 KsL[32 * 26];   // station keys
  __shared__ u16 VsL[32 * 44];   // rows 0-15: V_s^T; rows 16-31: 1.0

  const u16* Qbase = Qm + ((size_t)(h * 32 + b)) * 16384;
  const u16* QtsB = Qts + ((size_t)(h * 32 + b)) * 16384;
  const u16* Kbase = Kc + ((size_t)(h * 32 + b)) * 16384;
  const u16* Vbase = Vc + ((size_t)(h * 32 + b)) * 16384;
  const u16* KsB = Ks + (size_t)(h * 32 + b) * 512;
  const u16* VsB = Vs + (size_t)(h * 32 + b) * 512;

  uint4 ones4 = make_uint4(0x3F803F80u, 0x3F803F80u, 0x3F803F80u, 0x3F803F80u);

  // ---- stage station K/V + ones rows (visible after first barrier) ----
  if (tid < 64) {
    int key = tid >> 1, half = tid & 1;
    *(uint4*)&KsL[key * 26 + half * 8] = *(const uint4*)(KsB + key * 16 + half * 8);
  } else if (tid < 128) {
    int t = tid - 64;
    int d = t >> 2, kg = t & 3;
    *(uint4*)&VsL[d * 44 + kg * 8] = *(const uint4*)(VsB + d * 32 + kg * 8);
  } else if (tid < 192) {
    int t = tid - 128;  // VsL ones rows 16-31, cols 0-31: 64 x b128
    *(uint4*)&VsL[(16 + (t >> 2)) * 44 + (t & 3) * 8] = ones4;
  }
  // Vl ones rows 16-31, cols 0-127 (256 threads x b128); persist across
  // all kb stages (staging only writes rows 0-15).
  if (tid < 256)
    *(uint4*)&Vl[(16 + (tid >> 4)) * 140 + (tid & 15) * 8] = ones4;

  // T14 prefetch: main-loop tile 0, 8B per thread (512 threads)
  int skey = tid >> 2, shalf = tid & 3;   // K: 128 rows x 32B
  int sd = tid >> 5, skg = tid & 31;      // V: 16 rows x 256B (tile cols)
  uint2 kpre = *(const uint2*)(Kbase + (size_t)skey * 16 + shalf * 4);
  uint2 vpre = *(const uint2*)(Vbase + (size_t)sd * 1024 + skg * 4);

  int qw0 = qc * 256 + wave * 32;
  int qrow = qw0 + l31;

  f32x16 zero16;
#pragma unroll
  for (int i = 0; i < 16; ++i) zero16[i] = 0.f;

  // ---- station pass first: contrib[8] = (P_s V_s / la_s) rows ----
  U4B qf;
  qf.u = *(const uint4*)(QtsB + (size_t)qrow * 16 + l5 * 8);
  __syncthreads();  // KsL/VsL (+ones) visible
  float contrib[8];
  {
    U4B af;
    af.u = *(const uint4*)&KsL[l31 * 26 + l5 * 8];
    f32x16 c0 =
        __builtin_amdgcn_mfma_f32_32x32x16_bf16(af.b, qf.b, zero16, 0, 0, 0);
    uint32 w[8];
#pragma unroll
    for (int g = 0; g < 4; ++g) {
      float p0 = __builtin_amdgcn_exp2f(c0[4 * g + 0]);
      float p1 = __builtin_amdgcn_exp2f(c0[4 * g + 1]);
      float p2 = __builtin_amdgcn_exp2f(c0[4 * g + 2]);
      float p3 = __builtin_amdgcn_exp2f(c0[4 * g + 3]);
      int kb0 = 8 * g + 4 * l5;  // zero keys >= 21 (pad rows)
      p0 = (kb0 + 0 >= NST) ? 0.f : p0;
      p1 = (kb0 + 1 >= NST) ? 0.f : p1;
      p2 = (kb0 + 2 >= NST) ? 0.f : p2;
      p3 = (kb0 + 3 >= NST) ? 0.f : p3;
      w[2 * g] = pkperm(p0, p1);
      w[2 * g + 1] = pkperm(p2, p3);
    }
    plswap(w[0], w[2]); plswap(w[1], w[3]);
    plswap(w[4], w[6]); plswap(w[5], w[7]);
    U4B b1, b2, a1, a2;
    b1.u = make_uint4(w[0], w[1], w[2], w[3]);
    b2.u = make_uint4(w[4], w[5], w[6], w[7]);
    a1.u = *(const uint4*)&VsL[l31 * 44 + l5 * 8];
    a2.u = *(const uint4*)&VsL[l31 * 44 + 16 + l5 * 8];
    f32x16 acc2 =
        __builtin_amdgcn_mfma_f32_32x32x16_bf16(a1.b, b1.b, zero16, 0, 0, 0);
    acc2 = __builtin_amdgcn_mfma_f32_32x32x16_bf16(a2.b, b2.b, acc2, 0, 0, 0);
    float rla2 = __builtin_amdgcn_rcpf(acc2[8]);  // ones row m=16+4*l5
#pragma unroll
    for (int r = 0; r < 8; ++r) contrib[r] = acc2[r] * rla2;
  }

  // ---- main pass over Kc/Vc ----
  qf.u = *(const uint4*)(Qbase + (size_t)qrow * 16 + l5 * 8);
  f32x16 acc;
#pragma unroll
  for (int i = 0; i < 16; ++i) acc[i] = 0.f;

#pragma unroll 1
  for (int kb = 0; kb < 8; ++kb) {
    __syncthreads();  // previous tile's compute done reading Kl/Vl
    *(uint2*)&Kl[skey * 26 + shalf * 4] = kpre;
    *(uint2*)&Vl[sd * 140 + skg * 4] = vpre;
    if (kb < 7) {  // issue next tile; completes under this tile's compute
      int j0n = (kb + 1) * 128;
      kpre = *(const uint2*)(Kbase + (size_t)(j0n + skey) * 16 + shalf * 4);
      vpre = *(const uint2*)(Vbase + (size_t)sd * 1024 + j0n + skg * 4);
    }
    __syncthreads();

    // 2-deep pipeline: S(kt+1) issues before VALU block of kt
    U4B af0;
    af0.u = *(const uint4*)&Kl[l31 * 26 + l5 * 8];
    f32x16 c0 =
        __builtin_amdgcn_mfma_f32_32x32x16_bf16(af0.b, qf.b, zero16, 0, 0, 0);
#pragma unroll
    for (int kt = 0; kt < 4; ++kt) {
      f32x16 cn;
      if (kt < 3) {
        U4B afn;
        afn.u = *(const uint4*)&Kl[((kt + 1) * 32 + l31) * 26 + l5 * 8];
        cn = __builtin_amdgcn_mfma_f32_32x32x16_bf16(afn.b, qf.b, zero16, 0, 0, 0);
      }
      int key0 = kt * 32;
      bool masked = (kb == 0) && (kt == 0);
      uint32 w[8];
#pragma unroll
      for (int g = 0; g < 4; ++g) {
        float p0 = __builtin_amdgcn_exp2f(c0[4 * g + 0]);
        float p1 = __builtin_amdgcn_exp2f(c0[4 * g + 1]);
        float p2 = __builtin_amdgcn_exp2f(c0[4 * g + 2]);
        float p3 = __builtin_amdgcn_exp2f(c0[4 * g + 3]);
        if (masked) {  // key index of value r is r + 8*g + 4*l5; zero keys<21
          int kb0 = 8 * g + 4 * l5;
          p0 = (kb0 + 0 < NST) ? 0.f : p0;
          p1 = (kb0 + 1 < NST) ? 0.f : p1;
          p2 = (kb0 + 2 < NST) ? 0.f : p2;
          p3 = (kb0 + 3 < NST) ? 0.f : p3;
        }
        w[2 * g] = pkperm(p0, p1);
        w[2 * g + 1] = pkperm(p2, p3);
      }
      plswap(w[0], w[2]); plswap(w[1], w[3]);
      plswap(w[4], w[6]); plswap(w[5], w[7]);
      U4B b1, b2, a1, a2;
      b1.u = make_uint4(w[0], w[1], w[2], w[3]);
      b2.u = make_uint4(w[4], w[5], w[6], w[7]);
      a1.u = *(const uint4*)&Vl[l31 * 140 + key0 + l5 * 8];
      a2.u = *(const uint4*)&Vl[l31 * 140 + key0 + 16 + l5 * 8];
      acc = __builtin_amdgcn_mfma_f32_32x32x16_bf16(a1.b, b1.b, acc, 0, 0, 0);
      acc = __builtin_amdgcn_mfma_f32_32x32x16_bf16(a2.b, b2.b, acc, 0, 0, 0);
      if (kt < 3) c0 = cn;
    }
  }

  // ---- epilogue: heads bf16, layout [h][b][n][16] (block-contiguous) ----
  // acc regs 0-3: d = 4*l5 + r; regs 4-7: d = 8 + 4*l5 + (r-4);
  // regs 8-15: la rows (all equal) -> use acc[8].
  {
    float rla = __builtin_amdgcn_rcpf(acc[8]);
    bool tok = (qrow >= NST);
    float v0 = acc[0] * rla + (tok ? contrib[0] : 0.f);
    float v1 = acc[1] * rla + (tok ? contrib[1] : 0.f);
    float v2 = acc[2] * rla + (tok ? contrib[2] : 0.f);
    float v3 = acc[3] * rla + (tok ? contrib[3] : 0.f);
    float v4 = acc[4] * rla + (tok ? contrib[4] : 0.f);
    float v5 = acc[5] * rla + (tok ? contrib[5] : 0.f);
    float v6 = acc[6] * rla + (tok ? contrib[6] : 0.f);
    float v7 = acc[7] * rla + (tok ? contrib[7] : 0.f);
    u16* hrow = heads + (((size_t)(h * 32 + b)) * 1024 + qrow) * 16;
    *(uint2*)(hrow + 4 * l5) = make_uint2(pkbf(v0, v1), pkbf(v2, v3));
    *(uint2*)(hrow + 8 + 4 * l5) = make_uint2(pkbf(v4, v5), pkbf(v6, v7));
  }
}

// =====================================================================
extern "C" void kernel_launch(void* const* d_in, const int* in_sizes, int n_in,
                              void* d_out, int out_size, void* d_ws,
                              size_t ws_size, hipStream_t stream) {
  (void)in_sizes; (void)n_in; (void)out_size; (void)ws_size;
  const float* q     = (const float*)d_in[0];
  const float* hx    = (const float*)d_in[1];
  const float* W_qts = (const float*)d_in[2];  // W_query_custom   -> Q_ts
  const float* W_qtt = (const float*)d_in[3];  // W_query_custom_1 -> Q_tt
  const float* W_kc  = (const float*)d_in[4];
  const float* W_vc  = (const float*)d_in[5];
  const float* W_qst = (const float*)d_in[6];  // W_query_charge_1 -> Q_st
  const float* W_ks  = (const float*)d_in[7];
  const float* W_vs  = (const float*)d_in[8];
  const float* W_out = (const float*)d_in[9];

  char* ws = (char*)d_ws;
  u16* heads = (u16*)(ws + 0);          // bf16 heads [h][b][n][16]
  u16* Qm    = (u16*)(ws + 16777216);   // [h][b][1024][16]
  u16* Qts   = (u16*)(ws + 25165824);
  u16* Kc    = (u16*)(ws + 33554432);   // [h][b][1024][16]
  u16* Vc    = (u16*)(ws + 41943040);   // [h][b][16][1024] (transposed)
  u16* Ks    = (u16*)(ws + 50331648);   // [h][b][32][16]
  u16* Vs    = (u16*)(ws + 50593792);   // [h][b][16][32]
  u16* WtAll = (u16*)(ws + 50855936);   // 5 x 128x128 bf16

  hipLaunchKernelGGL(prep, dim3(552), dim3(256), 0, stream,
                     q, hx, W_qtt, W_qts, W_kc, W_vc, W_out, W_qst, W_ks, W_vs,
                     WtAll, Qm, Ks, Vs);
  hipLaunchKernelGGL(proj_pair, dim3(1024), dim3(256), 0, stream,
                     q, hx, WtAll, Qm, Qts, Kc, Vc);
  hipLaunchKernelGGL(attn_main, dim3(1024), dim3(512), 0, stream,
                     Qm, Qts, Kc, Vc, Ks, Vs, heads);
  hipLaunchKernelGGL(outproj, dim3(512), dim3(256), 0, stream,
                     heads, WtAll, (float*)d_out);
}

// Round 11
// 153.840 us; speedup vs baseline: 1.1600x; 1.0068x over previous
//
#include <hip/hip_runtime.h>

typedef __bf16 bf16x8 __attribute__((ext_vector_type(8)));
typedef float f32x4 __attribute__((ext_vector_type(4)));
typedef float f32x16 __attribute__((ext_vector_type(16)));
typedef unsigned int uint32;
typedef unsigned short u16;

#define NST 21
#define TOK 1003
#define SCL 0.3606737602222409f  // 0.25*log2(e); softmax = exp2(s), shift-free

union U4B { uint4 u; bf16x8 b; };

__device__ __forceinline__ uint32 pkbf(float a, float b) {  // RTNE pack
  uint32 ua = __float_as_uint(a), ub = __float_as_uint(b);
  ua += 0x7fffu + ((ua >> 16) & 1u);
  ub += 0x7fffu + ((ub >> 16) & 1u);
  return (ua >> 16) | (ub & 0xffff0000u);
}
__device__ __forceinline__ u16 bf1(float a) {
  uint32 u = __float_as_uint(a);
  u += 0x7fffu + ((u >> 16) & 1u);
  return (u16)(u >> 16);
}
// 1-instr truncating pack: lo16 = lo.hi16, hi16 = hi.hi16 (CK idiom)
__device__ __forceinline__ uint32 pkperm(float lo, float hi) {
  return __builtin_amdgcn_perm(__float_as_uint(hi), __float_as_uint(lo), 0x07060302u);
}
// half-wave swap: a' = {a.lanes0-31 | b.lanes0-31}, b' = {a.lanes32-63 | b.lanes32-63}
__device__ __forceinline__ void plswap(uint32& a, uint32& b) {
#if __has_builtin(__builtin_amdgcn_permlane32_swap)
  typedef unsigned int uu2 __attribute__((ext_vector_type(2)));
  uu2 r = __builtin_amdgcn_permlane32_swap(a, b, false, false);
  a = r.x; b = r.y;
#else
  asm volatile("v_permlane32_swap_b32 %0, %1" : "+v"(a), "+v"(b));
#endif
}

// =====================================================================
// prep: (a) 5 weight transposes -> bf16 WtAll (40 blocks, 8 per matrix),
// (b) station projections Q_st->Qm rows<21, K_s/V_s (+zero pad rows
// 21..32). grid 552 = 40 + 512
// =====================================================================
__global__ __launch_bounds__(256) void prep(
    const float* __restrict__ q, const float* __restrict__ hx,
    const float* __restrict__ W0, const float* __restrict__ W1,
    const float* __restrict__ W2, const float* __restrict__ W3,
    const float* __restrict__ W4, const float* __restrict__ Wqst,
    const float* __restrict__ Wks, const float* __restrict__ Wvs,
    u16* __restrict__ WtAll, u16* __restrict__ Qm,
    u16* __restrict__ Ks, u16* __restrict__ Vs) {
  int bid = blockIdx.x, tid = threadIdx.x;
  __shared__ float xq2[2][128], xh2[2][128];
  if (bid < 40) {
    int w = bid >> 3, seg = bid & 7;
    const float* W = (w == 0) ? W0 : (w == 1) ? W1 : (w == 2) ? W2
                     : (w == 3) ? W3 : W4;
    u16* dst = WtAll + w * 16384;
#pragma unroll
    for (int it = 0; it < 8; ++it) {
      int i = seg * 2048 + it * 256 + tid;  // 0..16383
      int inner = i & 127, outer = i >> 7;
      float v;
      if (w < 4) {
        int h = outer >> 4, k = outer & 15;
        v = W[h * 2048 + inner * 16 + k];
      } else {
        v = W[inner * 128 + outer];
      }
      dst[outer * 128 + inner] = bf1(v);
    }
  } else {
    int t2 = bid - 40;              // 0..511
    int sub = tid >> 7, col = tid & 127;
    int hh = col >> 4, k = col & 15;
    int bs2 = t2 * 2 + sub;         // 0..1023
    int b2 = bs2 >> 5, s = bs2 & 31;
    if (s < NST) {
      xq2[sub][col] = q[(size_t)(b2 * 1024 + s) * 128 + col];
      xh2[sub][col] = hx[(size_t)(b2 * 1024 + s) * 128 + col];
    }
    __syncthreads();
    if (s < NST) {
      const float* Wq = Wqst + hh * 2048 + k;
      const float* Wk = Wks + hh * 2048 + k;
      const float* Wv = Wvs + hh * 2048 + k;
      float dq = 0.f, dk_ = 0.f, dv = 0.f;
#pragma unroll 8
      for (int d = 0; d < 128; ++d) {
        float xq = xq2[sub][d], xh = xh2[sub][d];
        dq = fmaf(xq, Wq[d * 16], dq);
        dk_ = fmaf(xh, Wk[d * 16], dk_);
        dv = fmaf(xh, Wv[d * 16], dv);
      }
      Qm[(((size_t)hh * 32 + b2) * 1024 + s) * 16 + k] = bf1(dq * SCL);
      Ks[(((size_t)hh * 32 + b2) * 32 + s) * 16 + k] = bf1(dk_);
      Vs[(((size_t)hh * 32 + b2) * 16 + k) * 32 + s] = bf1(dv);
    } else {
      Ks[(((size_t)hh * 32 + b2) * 32 + s) * 16 + k] = 0;
      Vs[(((size_t)hh * 32 + b2) * 16 + k) * 32 + s] = 0;
    }
  }
}

// =====================================================================
// proj_pair: one block computes BOTH projections sharing an A tile.
// pg=0: q -> Qm (mode0: scaled, skip tok<21) and Qts (mode1: scaled)
// pg=1: hx -> Kc (mode2) and Vc (mode3: transposed [h][b][k16][n1024])
// Modes 0-2 use SWAPPED MFMA operands (A/B fragment layouts identical
// for 16x16x32) so each thread's 4 acc values are k-contiguous ->
// uint2 stores; a wave writes one contiguous 512B block per nt.
// grid 1024 = 2 x 512
// =====================================================================
__global__ __launch_bounds__(256) void proj_pair(
    const float* __restrict__ q, const float* __restrict__ hx,
    const u16* __restrict__ WtAll, u16* __restrict__ Qm,
    u16* __restrict__ Qts, u16* __restrict__ Kc, u16* __restrict__ Vc) {
  __shared__ u16 Wl[128 * 136];
  int pg = blockIdx.x >> 9, mb = blockIdx.x & 511;
  int m0 = mb * 64;
  const float* A = pg ? hx : q;
  int tid = threadIdx.x;
  int wave = tid >> 6, lane = tid & 63;
  int quad = lane >> 4, l15 = lane & 15;
  int mrow = m0 + wave * 16 + l15;

  U4B af[4];
#pragma unroll
  for (int dk = 0; dk < 4; ++dk) {
    const float* Af = A + (size_t)mrow * 128 + dk * 32 + quad * 8;
    float4 a = *(const float4*)Af;
    float4 b = *(const float4*)(Af + 4);
    af[dk].u = make_uint4(pkbf(a.x, a.y), pkbf(a.z, a.w),
                          pkbf(b.x, b.y), pkbf(b.z, b.w));
  }

  int gbase = m0 + wave * 16 + quad * 4;   // mode-3 path (unswapped)
  int bb = gbase >> 10, n0 = gbase & 1023;
  int token = mrow;                         // modes 0-2 path (swapped)
  int bb2 = token >> 10, tn = token & 1023;

#pragma unroll
  for (int s = 0; s < 2; ++s) {
    int mode = pg * 2 + s;
    const u16* WtG = WtAll + mode * 16384;
    if (s) __syncthreads();  // all Wl reads of s=0 done before restage
#pragma unroll
    for (int r = 0; r < 8; ++r) {
      int i = r * 256 + tid;
      int e = i >> 4, j = i & 15;
      *(uint4*)&Wl[e * 136 + j * 8] = *(const uint4*)(WtG + e * 128 + j * 8);
    }
    __syncthreads();

    f32x4 c[8];
#pragma unroll
    for (int nt = 0; nt < 8; ++nt)
#pragma unroll
      for (int r = 0; r < 4; ++r) c[nt][r] = 0.f;
#pragma unroll
    for (int dk = 0; dk < 4; ++dk)
#pragma unroll
      for (int nt = 0; nt < 8; ++nt) {
        U4B bg;
        bg.u = *(const uint4*)&Wl[(nt * 16 + l15) * 136 + dk * 32 + quad * 8];
        if (mode == 3)
          c[nt] = __builtin_amdgcn_mfma_f32_16x16x32_bf16(af[dk].b, bg.b, c[nt], 0, 0, 0);
        else
          c[nt] = __builtin_amdgcn_mfma_f32_16x16x32_bf16(bg.b, af[dk].b, c[nt], 0, 0, 0);
      }

    if (mode == 3) {
#pragma unroll
      for (int nt = 0; nt < 8; ++nt) {
        uint2 w2 = make_uint2(pkbf(c[nt][0], c[nt][1]), pkbf(c[nt][2], c[nt][3]));
        *(uint2*)(Vc + (((size_t)nt * 32 + bb) * 16 + l15) * 1024 + n0) = w2;
      }
    } else {
      float scale = (mode <= 1) ? SCL : 1.0f;
      u16* dstp = (mode == 0) ? Qm : (mode == 1) ? Qts : Kc;
      if (mode != 0 || tn >= NST) {  // prep owns station rows of Qm
#pragma unroll
        for (int nt = 0; nt < 8; ++nt) {
          uint2 w2 = make_uint2(pkbf(c[nt][0] * scale, c[nt][1] * scale),
                                pkbf(c[nt][2] * scale, c[nt][3] * scale));
          *(uint2*)(dstp + (((size_t)nt * 32 + bb2) * 1024 + tn) * 16 + quad * 4) = w2;
        }
      }
    }
  }
}

// =====================================================================
// outproj: out(64 x 128) f32 = heads_bf16(64x128) @ W_out^T
// heads is [h][b*1024+n][16] (head-major): column c = h*16+k ->
// h = dk*2+(quad>>1), k0 = (quad&1)*8.
// Swapped MFMA operands -> e-contiguous acc -> float4 stores.
// =====================================================================
__global__ __launch_bounds__(256) void outproj(
    const u16* __restrict__ heads, const u16* __restrict__ WtAll,
    float* __restrict__ out) {
  __shared__ u16 Wl[128 * 136];
  const u16* WtG = WtAll + 4 * 16384;
  int tid = threadIdx.x;
#pragma unroll
  for (int r = 0; r < 8; ++r) {
    int i = r * 256 + tid;
    int e = i >> 4, j = i & 15;
    *(uint4*)&Wl[e * 136 + j * 8] = *(const uint4*)(WtG + e * 128 + j * 8);
  }
  __syncthreads();
  int wave = tid >> 6, lane = tid & 63;
  int quad = lane >> 4, l15 = lane & 15;
  int m0 = blockIdx.x * 64;
  int mrow = m0 + wave * 16 + l15;

  f32x4 c[8];
#pragma unroll
  for (int nt = 0; nt < 8; ++nt)
#pragma unroll
    for (int r = 0; r < 4; ++r) c[nt][r] = 0.f;
#pragma unroll
  for (int dk = 0; dk < 4; ++dk) {
    U4B af;
    int h2 = dk * 2 + (quad >> 1);
    int k0 = (quad & 1) * 8;
    af.u = *(const uint4*)(heads + ((size_t)h2 * 32768 + mrow) * 16 + k0);
#pragma unroll
    for (int nt = 0; nt < 8; ++nt) {
      U4B bg;
      bg.u = *(const uint4*)&Wl[(nt * 16 + l15) * 136 + dk * 32 + quad * 8];
      c[nt] = __builtin_amdgcn_mfma_f32_16x16x32_bf16(bg.b, af.b, c[nt], 0, 0, 0);
    }
  }
  // thread holds out[token=mrow][e = nt*16 + quad*4 + r]
#pragma unroll
  for (int nt = 0; nt < 8; ++nt)
    *(f32x4*)(out + (size_t)mrow * 128 + nt * 16 + quad * 4) = c[nt];
}

// =====================================================================
// attn_main v7: v6b + double-buffered Kl/Vl -> ONE barrier per kb.
// Schedule per kb: ds_write buf[cb^1] (tile kb+1, prefetched a full
// compute phase ago) -> issue prefetch kb+2 -> compute 4 kt from
// buf[cb] -> barrier. Hazards: WAR (iter kb+1 writes buf[cb]) and RAW
// (iter kb+1 reads buf[cb^1]) both covered by the single barrier.
// Ones rows duplicated per Vl buffer at init (written once). LDS
// 35.7KB is free: 512-thr blocks are wave-slot-capped at 4 blocks/CU
// anyway. Math/epilogue byte-identical to verified r10 kernel.
// =====================================================================
__global__ __launch_bounds__(512, 4) void attn_main(
    const u16* __restrict__ Qm, const u16* __restrict__ Qts,
    const u16* __restrict__ Kc, const u16* __restrict__ Vc,
    const u16* __restrict__ Ks, const u16* __restrict__ Vs,
    u16* __restrict__ heads) {
  int bx = blockIdx.x;
  int hb = bx & 255, qc = bx >> 8;   // qc 0..3
  int h = hb >> 5, b = hb & 31;
  int tid = threadIdx.x;
  int wave = tid >> 6, lane = tid & 63;
  int l5 = lane >> 5, l31 = lane & 31;

  __shared__ u16 Kl[2][128 * 26];   // [key][26]: 52B rows, 13-bank step
  __shared__ u16 Vl[2][32 * 140];   // rows 0-15: V^T; rows 16-31: 1.0
  __shared__ u16 KsL[32 * 26];      // station keys
  __shared__ u16 VsL[32 * 44];      // rows 0-15: V_s^T; rows 16-31: 1.0

  const u16* Qbase = Qm + ((size_t)(h * 32 + b)) * 16384;
  const u16* QtsB = Qts + ((size_t)(h * 32 + b)) * 16384;
  const u16* Kbase = Kc + ((size_t)(h * 32 + b)) * 16384;
  const u16* Vbase = Vc + ((size_t)(h * 32 + b)) * 16384;
  const u16* KsB = Ks + (size_t)(h * 32 + b) * 512;
  const u16* VsB = Vs + (size_t)(h * 32 + b) * 512;

  uint4 ones4 = make_uint4(0x3F803F80u, 0x3F803F80u, 0x3F803F80u, 0x3F803F80u);

  // ---- stage station K/V + ones rows (visible after first barrier) ----
  if (tid < 64) {
    int key = tid >> 1, half = tid & 1;
    *(uint4*)&KsL[key * 26 + half * 8] = *(const uint4*)(KsB + key * 16 + half * 8);
  } else if (tid < 128) {
    int t = tid - 64;
    int d = t >> 2, kg = t & 3;
    *(uint4*)&VsL[d * 44 + kg * 8] = *(const uint4*)(VsB + d * 32 + kg * 8);
  } else if (tid < 192) {
    int t = tid - 128;  // VsL ones rows 16-31, cols 0-31: 64 x b128
    *(uint4*)&VsL[(16 + (t >> 2)) * 44 + (t & 3) * 8] = ones4;
  }
  // Vl ones rows 16-31 for BOTH buffers (512 threads = 2 x 256 x b128);
  // persist across all kb stages (staging only writes rows 0-15).
  {
    int vb = tid >> 8, t = tid & 255;
    *(uint4*)&Vl[vb][(16 + (t >> 4)) * 140 + (t & 15) * 8] = ones4;
  }

  // T14 prefetch: tile 0, 8B per thread (512 threads)
  int skey = tid >> 2, shalf = tid & 3;   // K: 128 rows x 32B
  int sd = tid >> 5, skg = tid & 31;      // V: 16 rows x 256B (tile cols)
  uint2 kpre = *(const uint2*)(Kbase + (size_t)skey * 16 + shalf * 4);
  uint2 vpre = *(const uint2*)(Vbase + (size_t)sd * 1024 + skg * 4);

  int qw0 = qc * 256 + wave * 32;
  int qrow = qw0 + l31;

  f32x16 zero16;
#pragma unroll
  for (int i = 0; i < 16; ++i) zero16[i] = 0.f;

  U4B qf;
  qf.u = *(const uint4*)(QtsB + (size_t)qrow * 16 + l5 * 8);

  // prologue: tile0 -> buf0; issue prefetch of tile1
  *(uint2*)&Kl[0][skey * 26 + shalf * 4] = kpre;
  *(uint2*)&Vl[0][sd * 140 + skg * 4] = vpre;
  kpre = *(const uint2*)(Kbase + (size_t)(128 + skey) * 16 + shalf * 4);
  vpre = *(const uint2*)(Vbase + (size_t)sd * 1024 + 128 + skg * 4);

  __syncthreads();  // KsL/VsL + ones + buf0 visible

  // ---- station pass: contrib[8] = (P_s V_s / la_s) rows ----
  float contrib[8];
  {
    U4B af;
    af.u = *(const uint4*)&KsL[l31 * 26 + l5 * 8];
    f32x16 c0 =
        __builtin_amdgcn_mfma_f32_32x32x16_bf16(af.b, qf.b, zero16, 0, 0, 0);
    uint32 w[8];
#pragma unroll
    for (int g = 0; g < 4; ++g) {
      float p0 = __builtin_amdgcn_exp2f(c0[4 * g + 0]);
      float p1 = __builtin_amdgcn_exp2f(c0[4 * g + 1]);
      float p2 = __builtin_amdgcn_exp2f(c0[4 * g + 2]);
      float p3 = __builtin_amdgcn_exp2f(c0[4 * g + 3]);
      int kb0 = 8 * g + 4 * l5;  // zero keys >= 21 (pad rows)
      p0 = (kb0 + 0 >= NST) ? 0.f : p0;
      p1 = (kb0 + 1 >= NST) ? 0.f : p1;
      p2 = (kb0 + 2 >= NST) ? 0.f : p2;
      p3 = (kb0 + 3 >= NST) ? 0.f : p3;
      w[2 * g] = pkperm(p0, p1);
      w[2 * g + 1] = pkperm(p2, p3);
    }
    plswap(w[0], w[2]); plswap(w[1], w[3]);
    plswap(w[4], w[6]); plswap(w[5], w[7]);
    U4B b1, b2, a1, a2;
    b1.u = make_uint4(w[0], w[1], w[2], w[3]);
    b2.u = make_uint4(w[4], w[5], w[6], w[7]);
    a1.u = *(const uint4*)&VsL[l31 * 44 + l5 * 8];
    a2.u = *(const uint4*)&VsL[l31 * 44 + 16 + l5 * 8];
    f32x16 acc2 =
        __builtin_amdgcn_mfma_f32_32x32x16_bf16(a1.b, b1.b, zero16, 0, 0, 0);
    acc2 = __builtin_amdgcn_mfma_f32_32x32x16_bf16(a2.b, b2.b, acc2, 0, 0, 0);
    float rla2 = __builtin_amdgcn_rcpf(acc2[8]);  // ones row m=16+4*l5
#pragma unroll
    for (int r = 0; r < 8; ++r) contrib[r] = acc2[r] * rla2;
  }

  // ---- main pass over Kc/Vc (dbuf, ONE barrier/kb, 2-deep kt pipe) ----
  qf.u = *(const uint4*)(Qbase + (size_t)qrow * 16 + l5 * 8);
  f32x16 acc;
#pragma unroll
  for (int i = 0; i < 16; ++i) acc[i] = 0.f;

#pragma unroll 1
  for (int kb = 0; kb < 8; ++kb) {
    int cb = kb & 1;
    if (kb < 7) {  // write prefetched tile kb+1 into the other buffer;
                   // WAR safe: buf[cb^1] readers finished before the
                   // barrier that ended iteration kb-1.
      *(uint2*)&Kl[cb ^ 1][skey * 26 + shalf * 4] = kpre;
      *(uint2*)&Vl[cb ^ 1][sd * 140 + skg * 4] = vpre;
      if (kb < 6) {
        int j0n = (kb + 2) * 128;
        kpre = *(const uint2*)(Kbase + (size_t)(j0n + skey) * 16 + shalf * 4);
        vpre = *(const uint2*)(Vbase + (size_t)sd * 1024 + j0n + skg * 4);
      }
    }

    // 2-deep pipeline: S(kt+1) issues before VALU block of kt
    U4B af0;
    af0.u = *(const uint4*)&Kl[cb][l31 * 26 + l5 * 8];
    f32x16 c0 =
        __builtin_amdgcn_mfma_f32_32x32x16_bf16(af0.b, qf.b, zero16, 0, 0, 0);
#pragma unroll
    for (int kt = 0; kt < 4; ++kt) {
      f32x16 cn;
      if (kt < 3) {
        U4B afn;
        afn.u = *(const uint4*)&Kl[cb][((kt + 1) * 32 + l31) * 26 + l5 * 8];
        cn = __builtin_amdgcn_mfma_f32_32x32x16_bf16(afn.b, qf.b, zero16, 0, 0, 0);
      }
      int key0 = kt * 32;
      bool masked = (kb == 0) && (kt == 0);
      uint32 w[8];
#pragma unroll
      for (int g = 0; g < 4; ++g) {
        float p0 = __builtin_amdgcn_exp2f(c0[4 * g + 0]);
        float p1 = __builtin_amdgcn_exp2f(c0[4 * g + 1]);
        float p2 = __builtin_amdgcn_exp2f(c0[4 * g + 2]);
        float p3 = __builtin_amdgcn_exp2f(c0[4 * g + 3]);
        if (masked) {  // key index of value r is r + 8*g + 4*l5; zero keys<21
          int kb0 = 8 * g + 4 * l5;
          p0 = (kb0 + 0 < NST) ? 0.f : p0;
          p1 = (kb0 + 1 < NST) ? 0.f : p1;
          p2 = (kb0 + 2 < NST) ? 0.f : p2;
          p3 = (kb0 + 3 < NST) ? 0.f : p3;
        }
        w[2 * g] = pkperm(p0, p1);
        w[2 * g + 1] = pkperm(p2, p3);
      }
      plswap(w[0], w[2]); plswap(w[1], w[3]);
      plswap(w[4], w[6]); plswap(w[5], w[7]);
      U4B b1, b2, a1, a2;
      b1.u = make_uint4(w[0], w[1], w[2], w[3]);
      b2.u = make_uint4(w[4], w[5], w[6], w[7]);
      a1.u = *(const uint4*)&Vl[cb][l31 * 140 + key0 + l5 * 8];
      a2.u = *(const uint4*)&Vl[cb][l31 * 140 + key0 + 16 + l5 * 8];
      acc = __builtin_amdgcn_mfma_f32_32x32x16_bf16(a1.b, b1.b, acc, 0, 0, 0);
      acc = __builtin_amdgcn_mfma_f32_32x32x16_bf16(a2.b, b2.b, acc, 0, 0, 0);
      if (kt < 3) c0 = cn;
    }
    __syncthreads();  // all reads of buf[cb] done AND buf[cb^1] staged
  }

  // ---- epilogue: heads bf16, layout [h][b][n][16] (block-contiguous) ----
  // acc regs 0-3: d = 4*l5 + r; regs 4-7: d = 8 + 4*l5 + (r-4);
  // regs 8-15: la rows (all equal) -> use acc[8].
  {
    float rla = __builtin_amdgcn_rcpf(acc[8]);
    bool tok = (qrow >= NST);
    float v0 = acc[0] * rla + (tok ? contrib[0] : 0.f);
    float v1 = acc[1] * rla + (tok ? contrib[1] : 0.f);
    float v2 = acc[2] * rla + (tok ? contrib[2] : 0.f);
    float v3 = acc[3] * rla + (tok ? contrib[3] : 0.f);
    float v4 = acc[4] * rla + (tok ? contrib[4] : 0.f);
    float v5 = acc[5] * rla + (tok ? contrib[5] : 0.f);
    float v6 = acc[6] * rla + (tok ? contrib[6] : 0.f);
    float v7 = acc[7] * rla + (tok ? contrib[7] : 0.f);
    u16* hrow = heads + (((size_t)(h * 32 + b)) * 1024 + qrow) * 16;
    *(uint2*)(hrow + 4 * l5) = make_uint2(pkbf(v0, v1), pkbf(v2, v3));
    *(uint2*)(hrow + 8 + 4 * l5) = make_uint2(pkbf(v4, v5), pkbf(v6, v7));
  }
}

// =====================================================================
extern "C" void kernel_launch(void* const* d_in, const int* in_sizes, int n_in,
                              void* d_out, int out_size, void* d_ws,
                              size_t ws_size, hipStream_t stream) {
  (void)in_sizes; (void)n_in; (void)out_size; (void)ws_size;
  const float* q     = (const float*)d_in[0];
  const float* hx    = (const float*)d_in[1];
  const float* W_qts = (const float*)d_in[2];  // W_query_custom   -> Q_ts
  const float* W_qtt = (const float*)d_in[3];  // W_query_custom_1 -> Q_tt
  const float* W_kc  = (const float*)d_in[4];
  const float* W_vc  = (const float*)d_in[5];
  const float* W_qst = (const float*)d_in[6];  // W_query_charge_1 -> Q_st
  const float* W_ks  = (const float*)d_in[7];
  const float* W_vs  = (const float*)d_in[8];
  const float* W_out = (const float*)d_in[9];

  char* ws = (char*)d_ws;
  u16* heads = (u16*)(ws + 0);          // bf16 heads [h][b][n][16]
  u16* Qm    = (u16*)(ws + 16777216);   // [h][b][1024][16]
  u16* Qts   = (u16*)(ws + 25165824);
  u16* Kc    = (u16*)(ws + 33554432);   // [h][b][1024][16]
  u16* Vc    = (u16*)(ws + 41943040);   // [h][b][16][1024] (transposed)
  u16* Ks    = (u16*)(ws + 50331648);   // [h][b][32][16]
  u16* Vs    = (u16*)(ws + 50593792);   // [h][b][16][32]
  u16* WtAll = (u16*)(ws + 50855936);   // 5 x 128x128 bf16

  hipLaunchKernelGGL(prep, dim3(552), dim3(256), 0, stream,
                     q, hx, W_qtt, W_qts, W_kc, W_vc, W_out, W_qst, W_ks, W_vs,
                     WtAll, Qm, Ks, Vs);
  hipLaunchKernelGGL(proj_pair, dim3(1024), dim3(256), 0, stream,
                     q, hx, WtAll, Qm, Qts, Kc, Vc);
  hipLaunchKernelGGL(attn_main, dim3(1024), dim3(512), 0, stream,
                     Qm, Qts, Kc, Vc, Ks, Vs, heads);
  hipLaunchKernelGGL(outproj, dim3(512), dim3(256), 0, stream,
                     heads, WtAll, (float*)d_out);
}